// Round 4
// baseline (269.199 us; speedup 1.0000x reference)
//
#include <hip/hip_runtime.h>

#define N_SAMP   1024
#define IN_F     512
#define OUT_F    512
#define N_HEADS  32
#define N_SPLITS 4
#define N_GROUPS (N_HEADS * N_SPLITS)
#define DELTA_SCALE 0.1f

#define KSPLIT   8
#define KROWS    (IN_F / KSPLIT)   // 64 k-rows per block
#define JC       16                // samples per chunk (P(nc<=16) ~ 0.996)

// R9: cross-block k-split with full-row streaming + two-phase reduce.
//
// Evidence chain: R7 (256B segments) = 1.07 TB/s fetch; R8 (1KB segments,
// but 2x duplication + barrier-per-step) = 1.83 TB/s. Hypothesis: fetch
// efficiency scales with contiguous row coverage; duplication and barriers
// ate R8's win. k is the ONLY split axis that partitions W/D bytes without
// narrowing rows.
//
//   lms_partial: block = (combo g, k-eighth kb), 1024 blocks x 256 thr.
//     Block streams FULL 2KB rows of W[h] and D[g] over its 64-row range,
//     monotonically in k, each byte read exactly once per dispatch.
//     Thread owns col-pair (2*tid) for ALL 64 rows -> acc is final, no
//     in-block reduce, no LDS weight staging, k-loop is BARRIER-FREE.
//     Per 4-row batch: 8 float2 loads (dist-1 dbuf), 8 v_fma combine
//     rc = w + 0.1*d, 16 wave-uniform ds_read_b128 X broadcasts, 128 fmac.
//     Partial written to ws[kb][sample][col] (coalesced 2KB/j).
//     XCD swizzle: logical = (b&7)*128 + b>>3 pins each head's 32 blocks
//     (4 splits x 8 kb) to one XCD -> W[h] (1MB) resident in that L2.
//   lms_reduce: out[i][c] = bias[head[i]][c] + sum_kb ws[kb][i][c].
//     16 MB read + 2 MB write, trivially coalesced.
//
// LDS: Xs 4KB + list 4KB = 8.3 KB (never binding). VGPR ~95 (acc 32 +
// dbuf 32 + rc 8 + addressing) -> 4 waves/SIMD at launch_bounds(256,4).
// Falls back to the verified R7 fused kernel if ws_size < 16 MB.

__global__ __launch_bounds__(256, 4) void lms_partial(
    const float* __restrict__ X, const int* __restrict__ head_ix,
    const int* __restrict__ split_ix, const float* __restrict__ W,
    const float* __restrict__ D, float* __restrict__ ws)
{
    __shared__ float Xs[JC][KROWS];    // 4 KB, zero-padded invalid rows
    __shared__ int   list[N_SAMP];     // 4 KB
    __shared__ int   wsum[4];

    // XCD-pinning swizzle (1024 % 8 == 0 -> bijective)
    const int b       = blockIdx.x;
    const int logical = (b & 7) * 128 + (b >> 3);
    const int g       = logical >> 3;        // combo = h*N_SPLITS + s
    const int kb      = logical & 7;         // k-eighth
    const int h       = g >> 2;              // N_SPLITS == 4

    const int tid  = threadIdx.x;
    const int lane = tid & 63;
    const int wave = tid >> 6;

    // deterministic order-preserving compaction of samples matching combo g
    int run = 0;
    for (int r = 0; r < N_SAMP / 256; ++r) {
        const int i   = r * 256 + tid;
        const int key = head_ix[i] * N_SPLITS + split_ix[i];
        const bool hit = (key == g);
        const unsigned long long m = __ballot(hit);
        if (lane == 0) wsum[wave] = __popcll(m);
        __syncthreads();
        int base = run;
        for (int w = 0; w < 4; ++w)
            if (w < wave) base += wsum[w];
        if (hit)
            list[base + __popcll(m & ((1ULL << lane) - 1ULL))] = i;
        run += wsum[0] + wsum[1] + wsum[2] + wsum[3];
        __syncthreads();               // wsum consumed before next round
    }
    const int total = run;
    if (total == 0) return;            // block-uniform

    // thread's col-pair base within the block's 64-row k-panel
    const float* wq = W + (size_t)h * (IN_F * OUT_F)
                    + (size_t)(kb * KROWS) * OUT_F + 2 * tid;
    const float* dq = D + (size_t)g * (IN_F * OUT_F)
                    + (size_t)(kb * KROWS) * OUT_F + 2 * tid;

    for (int cb = 0; cb < total; cb += JC) {
        const int nc = min(total - cb, JC);

        __syncthreads();               // Xs from previous chunk consumed
        // stage Xs[s][0..63] = X[list[cb+s]][kb*64 .. +64): 256 float4
        {
            const int s  = tid >> 4;   // 0..15
            const int qq = tid & 15;   // float4 index within 64 floats
            float4 v = make_float4(0.f, 0.f, 0.f, 0.f);
            if (s < nc)
                v = *(const float4*)(X + (size_t)list[cb + s] * IN_F
                                     + kb * KROWS + qq * 4);
            *(float4*)(&Xs[s][qq * 4]) = v;
        }
        __syncthreads();

        float2 acc[JC];
#pragma unroll
        for (int j = 0; j < JC; ++j) { acc[j].x = 0.f; acc[j].y = 0.f; }

        // distance-1 double-buffered 4-row batches; per load inst a wave
        // covers 512B contiguous and the block covers the FULL 2KB row.
        float2 wr[2][4], dr[2][4];
#pragma unroll
        for (int f = 0; f < 4; ++f) {
            wr[0][f] = *(const float2*)(wq + (size_t)f * OUT_F);
            dr[0][f] = *(const float2*)(dq + (size_t)f * OUT_F);
        }

        constexpr int NB = KROWS / 4;  // 16 batches
#pragma unroll 2
        for (int bt = 0; bt < NB; ++bt) {
            const int cur = bt & 1, nxt = cur ^ 1;
            // issue L(t+1) before consuming L(t) (clamped tail: redundant
            // L1-hit re-load keeps the body branch-free)
            const int nr = (bt + 1 < NB) ? (bt + 1) * 4 : bt * 4;
#pragma unroll
            for (int f = 0; f < 4; ++f) {
                wr[nxt][f] = *(const float2*)(wq + (size_t)(nr + f) * OUT_F);
                dr[nxt][f] = *(const float2*)(dq + (size_t)(nr + f) * OUT_F);
            }

            float2 rc[4];
#pragma unroll
            for (int f = 0; f < 4; ++f) {
                rc[f].x = wr[cur][f].x + DELTA_SCALE * dr[cur][f].x;
                rc[f].y = wr[cur][f].y + DELTA_SCALE * dr[cur][f].y;
            }

#pragma unroll
            for (int j = 0; j < JC; ++j) {
                const float4 xv = *(const float4*)(&Xs[j][bt * 4]); // bcast
                acc[j].x += xv.x * rc[0].x; acc[j].y += xv.x * rc[0].y;
                acc[j].x += xv.y * rc[1].x; acc[j].y += xv.y * rc[1].y;
                acc[j].x += xv.z * rc[2].x; acc[j].y += xv.z * rc[2].y;
                acc[j].x += xv.w * rc[3].x; acc[j].y += xv.w * rc[3].y;
            }
        }

        // epilogue: acc is the block's final k-partial -> straight to ws
#pragma unroll
        for (int j = 0; j < JC; ++j) {
            if (j < nc) {
                float* op = ws + ((size_t)kb * N_SAMP + list[cb + j]) * OUT_F
                          + 2 * tid;
                *(float2*)op = acc[j];
            }
        }
    }
}

// out[i][c] = bias[head_ix[i]][c] + sum_kb ws[kb][i][c]
__global__ __launch_bounds__(256, 4) void lms_reduce(
    const float* __restrict__ ws, const int* __restrict__ head_ix,
    const float* __restrict__ bias, float* __restrict__ out)
{
    const int gid = blockIdx.x * 256 + threadIdx.x;
    const int i   = gid >> 7;          // sample
    const int c4  = gid & 127;         // float4 index within 512 cols
    const int h   = head_ix[i];

    float4 s = *(const float4*)(bias + (size_t)h * OUT_F + 4 * c4);
#pragma unroll
    for (int kb = 0; kb < KSPLIT; ++kb) {
        const float4 p = *(const float4*)(ws + ((size_t)kb * N_SAMP + i) * OUT_F
                                          + 4 * c4);
        s.x += p.x; s.y += p.y; s.z += p.z; s.w += p.w;
    }
    *(float4*)(out + (size_t)i * OUT_F + 4 * c4) = s;
}

// ---------------------------------------------------------------------------
// Fallback (verified R7 fused, 86 us): used only if ws_size < 16 MB.
__global__ __launch_bounds__(256, 4) void lms_fused(
    const float* __restrict__ X, const int* __restrict__ head_ix,
    const int* __restrict__ split_ix, const float* __restrict__ W,
    const float* __restrict__ D, const float* __restrict__ bias,
    float* __restrict__ out)
{
    constexpr int J    = 16;
    constexpr int KQ   = 8;
    constexpr int KT   = IN_F / KQ;
    constexpr int NST  = KT / 4;
    constexpr int NOUT = (J * 32) / 256;

    __shared__ float buf[J * IN_F];
    __shared__ int   list[N_SAMP];
    __shared__ int   wsum[4];

    const int g    = blockIdx.y;
    const int h    = g >> 2;
    const int c0   = blockIdx.x * 64;
    const int tid  = threadIdx.x;
    const int c2   = tid & 31;
    const int kq   = tid >> 5;
    const int lane = tid & 63;
    const int wave = tid >> 6;

    int run = 0;
    for (int r = 0; r < N_SAMP / 256; ++r) {
        const int i   = r * 256 + tid;
        const int key = head_ix[i] * N_SPLITS + split_ix[i];
        const bool hit = (key == g);
        const unsigned long long m = __ballot(hit);
        if (lane == 0) wsum[wave] = __popcll(m);
        __syncthreads();
        int base = run;
        for (int w = 0; w < 4; ++w)
            if (w < wave) base += wsum[w];
        if (hit)
            list[base + __popcll(m & ((1ULL << lane) - 1ULL))] = i;
        run += wsum[0] + wsum[1] + wsum[2] + wsum[3];
        __syncthreads();
    }
    const int total = run;
    if (total == 0) return;

    const size_t roff = (size_t)(kq * KT) * OUT_F + c0 + c2 * 2;
    const float* wp = W + (size_t)h * (IN_F * OUT_F) + roff;
    const float* dp = D + (size_t)g * (IN_F * OUT_F) + roff;

    for (int s0 = 0; s0 < total; s0 += J) {
        const int nc = min(total - s0, J);
        __syncthreads();
        for (int i = tid; i < J * (IN_F / 4); i += 256) {
            const int s = i >> 7, q = i & 127;
            float4 v = make_float4(0.f, 0.f, 0.f, 0.f);
            if (s < nc)
                v = *(const float4*)(X + (size_t)list[s0 + s] * IN_F + q * 4);
            *(float4*)(&buf[s * IN_F + q * 4]) = v;
        }
        __syncthreads();

        float2 acc[J];
#pragma unroll
        for (int j = 0; j < J; ++j) { acc[j].x = 0.f; acc[j].y = 0.f; }

        float2 wb[2][4], db[2][4];
#pragma unroll
        for (int u = 0; u < 4; ++u) {
            wb[0][u] = *(const float2*)(wp + (size_t)u * OUT_F);
            db[0][u] = *(const float2*)(dp + (size_t)u * OUT_F);
        }

#pragma unroll 2
        for (int st = 0; st < NST; ++st) {
            const int nx = (st + 1 < NST) ? st + 1 : NST - 1;
            const int nb = (st + 1) & 1, cb = st & 1;
            const float* wn = wp + (size_t)(nx * 4) * OUT_F;
            const float* dn = dp + (size_t)(nx * 4) * OUT_F;
#pragma unroll
            for (int u = 0; u < 4; ++u) {
                wb[nb][u] = *(const float2*)(wn + (size_t)u * OUT_F);
                db[nb][u] = *(const float2*)(dn + (size_t)u * OUT_F);
            }
            float2 rc[4];
#pragma unroll
            for (int u = 0; u < 4; ++u) {
                rc[u].x = wb[cb][u].x + DELTA_SCALE * db[cb][u].x;
                rc[u].y = wb[cb][u].y + DELTA_SCALE * db[cb][u].y;
            }
            const float* xb = &buf[kq * KT + st * 4];
#pragma unroll
            for (int j = 0; j < J; ++j) {
                const float4 xv = *(const float4*)(xb + j * IN_F);
                acc[j].x += xv.x * rc[0].x; acc[j].y += xv.x * rc[0].y;
                acc[j].x += xv.y * rc[1].x; acc[j].y += xv.y * rc[1].y;
                acc[j].x += xv.z * rc[2].x; acc[j].y += xv.z * rc[2].y;
                acc[j].x += xv.w * rc[3].x; acc[j].y += xv.w * rc[3].y;
            }
        }

        __syncthreads();
        float2* Red = (float2*)buf;
#pragma unroll
        for (int j = 0; j < J; ++j)
            Red[(kq * J + j) * 32 + c2] = acc[j];
        __syncthreads();

#pragma unroll
        for (int t = 0; t < NOUT; ++t) {
            const int oi = t * 256 + tid;
            const int j = oi >> 5, cc = oi & 31;
            if (j < nc) {
                float2 s = make_float2(0.f, 0.f);
#pragma unroll
                for (int q = 0; q < KQ; ++q) {
                    const float2 r = Red[(q * J + j) * 32 + cc];
                    s.x += r.x; s.y += r.y;
                }
                const float2 bv =
                    *(const float2*)(bias + (size_t)h * OUT_F + c0 + cc * 2);
                float* op = out + (size_t)list[s0 + j] * OUT_F + c0 + cc * 2;
                float2 res;
                res.x = s.x + bv.x;
                res.y = s.y + bv.y;
                *(float2*)op = res;
            }
        }
    }
}

extern "C" void kernel_launch(void* const* d_in, const int* in_sizes, int n_in,
                              void* d_out, int out_size, void* d_ws, size_t ws_size,
                              hipStream_t stream) {
    const float* X        = (const float*)d_in[0];
    const int*   head_ix  = (const int*)d_in[1];
    const int*   split_ix = (const int*)d_in[2];
    const float* W        = (const float*)d_in[3];
    const float* D        = (const float*)d_in[4];
    const float* bias     = (const float*)d_in[5];
    float*       out      = (float*)d_out;

    const size_t ws_need = (size_t)KSPLIT * N_SAMP * OUT_F * sizeof(float); // 16 MB
    if (ws_size >= ws_need) {
        float* ws = (float*)d_ws;
        // 1024 blocks (128 combos x 8 k-eighths), 4/CU, barrier-free k-loop
        lms_partial<<<dim3(N_GROUPS * KSPLIT), 256, 0, stream>>>(
            X, head_ix, split_ix, W, D, ws);
        // 512 blocks: 16 MB read + 2 MB write, bias folded
        lms_reduce<<<dim3((N_SAMP * OUT_F / 4) / 256), 256, 0, stream>>>(
            ws, head_ix, bias, out);
    } else {
        // verified R7 fused fallback
        dim3 gf(OUT_F / 64, N_GROUPS);
        lms_fused<<<gf, 256, 0, stream>>>(X, head_ix, split_ix, W, D, bias, out);
    }
}

// Round 5
// 254.013 us; speedup vs baseline: 1.0598x; 1.0598x over previous
//
#include <hip/hip_runtime.h>

#define N_SAMP   1024
#define IN_F     512
#define OUT_F    512
#define N_HEADS  32
#define N_SPLITS 4
#define N_GROUPS (N_HEADS * N_SPLITS)
#define DELTA_SCALE 0.1f

#define NKB      4                 // k-quarter blocks per combo
#define KR2      128               // k rows per block
#define KRH      64                // k rows per thread (kh half)
#define NPLANES  8                 // NKB * 2 kh-halves
#define JC       16                // samples per chunk (P(nc<=16) ~ 0.996)

// R10: cross-block k-split (R9 structure) + 16B/lane float4 W/D requests
// (R8's only good property).
//
// Evidence: logical supply tracked request width across R7/R8/R9
// (8B/lane -> 2.4-3.0 TB/s; 16B/lane -> 4.5 TB/s), NOT row contiguity
// (R9 falsified that). All variants are supply-bound (VALUBusy ~10%,
// queueing math: 64KB/CU inflight / 3.9 B/cyc/CU = the observed ~16k-cycle
// per-batch stall). So: keep zero-duplication streaming, widen every
// W/D load to dwordx4 with full 1KB-contiguous wave coverage.
//
//   lms_partial4: block = (combo g, k-quarter kb), 512 blocks x 256 thr.
//     thread = (col-quad c4 = tid&127, k-half kh = tid>>7): owns cols
//     [4c4,4c4+4) over 64 rows -> acc is final (no in-block reduce, no
//     barriers in the k-loop). Per 4-row batch: 4+4 float4 loads (dist-1
//     dbuf, compile-time buffer indices via unroll-2), rc = w + 0.1*d,
//     16 wave-uniform ds_read_b128 X broadcasts, 256 fmac.
//     Partial -> ws[plane=kb*2+kh][sample][4c4] (1KB/wave stores).
//     XCD pinning: b&7 = XCD; 64 blocks/XCD = 4 heads x 4 splits x 4 kb
//     -> each head's W panel L2-reused 4x within one XCD.
//   lms_reduce: out[i][c] = bias[head[i]][c] + sum_p ws[p][i][c]  (R9,
//     verified).
//
// LDS 12.3 KB; VGPR ~160 (acc 64 + dbuf 64 + rc 16 + addr) -> fine at
// 2 blocks/CU (grid-limited). Falls back to verified R7 fused if ws small.

__global__ __launch_bounds__(256, 2) void lms_partial4(
    const float* __restrict__ X, const int* __restrict__ head_ix,
    const int* __restrict__ split_ix, const float* __restrict__ W,
    const float* __restrict__ D, float* __restrict__ ws)
{
    __shared__ float Xs[JC][KR2];      // 8 KB, zero-padded invalid rows
    __shared__ int   list[N_SAMP];     // 4 KB
    __shared__ int   wsum[4];

    // XCD pinning (round-robin heuristic: XCD = blockIdx % 8; speed-only)
    const int b   = blockIdx.x;
    const int x   = b & 7;                  // target XCD
    const int j5  = b >> 3;                 // [0,64) within XCD
    const int h   = x | ((j5 & 3) << 3);    // heads x, x+8, x+16, x+24
    const int s   = (j5 >> 2) & 3;
    const int kb  = j5 >> 4;                // k-quarter [0,4)
    const int g   = h * N_SPLITS + s;

    const int tid  = threadIdx.x;
    const int c4   = tid & 127;             // col-quad: cols 4*c4 .. +3
    const int kh   = tid >> 7;              // k-half of the block's 128 rows
    const int lane = tid & 63;
    const int wave = tid >> 6;

    // deterministic order-preserving compaction of samples matching combo g
    int run = 0;
    for (int r = 0; r < N_SAMP / 256; ++r) {
        const int i   = r * 256 + tid;
        const int key = head_ix[i] * N_SPLITS + split_ix[i];
        const bool hit = (key == g);
        const unsigned long long m = __ballot(hit);
        if (lane == 0) wsum[wave] = __popcll(m);
        __syncthreads();
        int base = run;
        for (int w = 0; w < 4; ++w)
            if (w < wave) base += wsum[w];
        if (hit)
            list[base + __popcll(m & ((1ULL << lane) - 1ULL))] = i;
        run += wsum[0] + wsum[1] + wsum[2] + wsum[3];
        __syncthreads();               // wsum consumed before next round
    }
    const int total = run;
    if (total == 0) return;            // block-uniform

    const int krow0 = kb * KR2 + kh * KRH;     // thread's first k row
    const float* wq = W + (size_t)h * (IN_F * OUT_F)
                    + (size_t)krow0 * OUT_F + 4 * c4;
    const float* dq = D + (size_t)g * (IN_F * OUT_F)
                    + (size_t)krow0 * OUT_F + 4 * c4;
    const int plane = kb * 2 + kh;

    for (int cb = 0; cb < total; cb += JC) {
        const int nc = min(total - cb, JC);

        __syncthreads();               // Xs from previous chunk consumed
        // stage Xs[s][0..127] = X[list[cb+s]][kb*128 .. +128): 512 float4
        for (int f = 0; f < 2; ++f) {
            const int fid = f * 256 + tid;     // [0,512)
            const int ss = fid >> 5, qq = fid & 31;
            float4 v = make_float4(0.f, 0.f, 0.f, 0.f);
            if (ss < nc)
                v = *(const float4*)(X + (size_t)list[cb + ss] * IN_F
                                     + kb * KR2 + qq * 4);
            *(float4*)(&Xs[ss][qq * 4]) = v;
        }
        __syncthreads();

        float4 acc[JC];
#pragma unroll
        for (int j = 0; j < JC; ++j)
            acc[j] = make_float4(0.f, 0.f, 0.f, 0.f);

        // distance-1 double-buffered 4-row batches; each load inst is a
        // dwordx4 and each wave covers 1KB contiguous.
        float4 wr[2][4], dr[2][4];
#pragma unroll
        for (int f = 0; f < 4; ++f) {
            wr[0][f] = *(const float4*)(wq + (size_t)f * OUT_F);
            dr[0][f] = *(const float4*)(dq + (size_t)f * OUT_F);
        }

        constexpr int NB = KRH / 4;    // 16 batches
#pragma unroll 2
        for (int bt = 0; bt < NB; ++bt) {
            const int cur = bt & 1, nxt = cur ^ 1;  // compile-time (unroll 2)
            // issue L(t+1) before consuming L(t) (clamped tail: redundant
            // L1-hit re-load keeps the body branch-free)
            const int nr = (bt + 1 < NB) ? (bt + 1) * 4 : bt * 4;
#pragma unroll
            for (int f = 0; f < 4; ++f) {
                wr[nxt][f] = *(const float4*)(wq + (size_t)(nr + f) * OUT_F);
                dr[nxt][f] = *(const float4*)(dq + (size_t)(nr + f) * OUT_F);
            }

            float4 rc[4];
#pragma unroll
            for (int f = 0; f < 4; ++f) {
                rc[f].x = wr[cur][f].x + DELTA_SCALE * dr[cur][f].x;
                rc[f].y = wr[cur][f].y + DELTA_SCALE * dr[cur][f].y;
                rc[f].z = wr[cur][f].z + DELTA_SCALE * dr[cur][f].z;
                rc[f].w = wr[cur][f].w + DELTA_SCALE * dr[cur][f].w;
            }

#pragma unroll
            for (int j = 0; j < JC; ++j) {
                const float4 xv =
                    *(const float4*)(&Xs[j][kh * KRH + bt * 4]);  // bcast
                acc[j].x += xv.x * rc[0].x; acc[j].y += xv.x * rc[0].y;
                acc[j].z += xv.x * rc[0].z; acc[j].w += xv.x * rc[0].w;
                acc[j].x += xv.y * rc[1].x; acc[j].y += xv.y * rc[1].y;
                acc[j].z += xv.y * rc[1].z; acc[j].w += xv.y * rc[1].w;
                acc[j].x += xv.z * rc[2].x; acc[j].y += xv.z * rc[2].y;
                acc[j].z += xv.z * rc[2].z; acc[j].w += xv.z * rc[2].w;
                acc[j].x += xv.w * rc[3].x; acc[j].y += xv.w * rc[3].y;
                acc[j].z += xv.w * rc[3].z; acc[j].w += xv.w * rc[3].w;
            }
        }

        // epilogue: acc is the thread's final k-partial -> straight to ws
        // (per plane, 128 threads cover the full 2KB row; 1KB/wave stores)
#pragma unroll
        for (int j = 0; j < JC; ++j) {
            if (j < nc) {
                float* op = ws + ((size_t)plane * N_SAMP + list[cb + j]) * OUT_F
                          + 4 * c4;
                *(float4*)op = acc[j];
            }
        }
    }
}

// out[i][c] = bias[head_ix[i]][c] + sum_p ws[p][i][c]   (verified in R9)
__global__ __launch_bounds__(256, 4) void lms_reduce(
    const float* __restrict__ ws, const int* __restrict__ head_ix,
    const float* __restrict__ bias, float* __restrict__ out)
{
    const int gid = blockIdx.x * 256 + threadIdx.x;
    const int i   = gid >> 7;          // sample
    const int c4  = gid & 127;         // float4 index within 512 cols
    const int h   = head_ix[i];

    float4 s = *(const float4*)(bias + (size_t)h * OUT_F + 4 * c4);
#pragma unroll
    for (int p = 0; p < NPLANES; ++p) {
        const float4 v = *(const float4*)(ws + ((size_t)p * N_SAMP + i) * OUT_F
                                          + 4 * c4);
        s.x += v.x; s.y += v.y; s.z += v.z; s.w += v.w;
    }
    *(float4*)(out + (size_t)i * OUT_F + 4 * c4) = s;
}

// ---------------------------------------------------------------------------
// Fallback (verified R7 fused, 86 us/dispatch): used only if ws too small.
__global__ __launch_bounds__(256, 4) void lms_fused(
    const float* __restrict__ X, const int* __restrict__ head_ix,
    const int* __restrict__ split_ix, const float* __restrict__ W,
    const float* __restrict__ D, const float* __restrict__ bias,
    float* __restrict__ out)
{
    constexpr int J    = 16;
    constexpr int KQ   = 8;
    constexpr int KT   = IN_F / KQ;
    constexpr int NST  = KT / 4;
    constexpr int NOUT = (J * 32) / 256;

    __shared__ float buf[J * IN_F];
    __shared__ int   list[N_SAMP];
    __shared__ int   wsum[4];

    const int g    = blockIdx.y;
    const int h    = g >> 2;
    const int c0   = blockIdx.x * 64;
    const int tid  = threadIdx.x;
    const int c2   = tid & 31;
    const int kq   = tid >> 5;
    const int lane = tid & 63;
    const int wave = tid >> 6;

    int run = 0;
    for (int r = 0; r < N_SAMP / 256; ++r) {
        const int i   = r * 256 + tid;
        const int key = head_ix[i] * N_SPLITS + split_ix[i];
        const bool hit = (key == g);
        const unsigned long long m = __ballot(hit);
        if (lane == 0) wsum[wave] = __popcll(m);
        __syncthreads();
        int base = run;
        for (int w = 0; w < 4; ++w)
            if (w < wave) base += wsum[w];
        if (hit)
            list[base + __popcll(m & ((1ULL << lane) - 1ULL))] = i;
        run += wsum[0] + wsum[1] + wsum[2] + wsum[3];
        __syncthreads();
    }
    const int total = run;
    if (total == 0) return;

    const size_t roff = (size_t)(kq * KT) * OUT_F + c0 + c2 * 2;
    const float* wp = W + (size_t)h * (IN_F * OUT_F) + roff;
    const float* dp = D + (size_t)g * (IN_F * OUT_F) + roff;

    for (int s0 = 0; s0 < total; s0 += J) {
        const int nc = min(total - s0, J);
        __syncthreads();
        for (int i = tid; i < J * (IN_F / 4); i += 256) {
            const int s = i >> 7, q = i & 127;
            float4 v = make_float4(0.f, 0.f, 0.f, 0.f);
            if (s < nc)
                v = *(const float4*)(X + (size_t)list[s0 + s] * IN_F + q * 4);
            *(float4*)(&buf[s * IN_F + q * 4]) = v;
        }
        __syncthreads();

        float2 acc[J];
#pragma unroll
        for (int j = 0; j < J; ++j) { acc[j].x = 0.f; acc[j].y = 0.f; }

        float2 wb[2][4], db[2][4];
#pragma unroll
        for (int u = 0; u < 4; ++u) {
            wb[0][u] = *(const float2*)(wp + (size_t)u * OUT_F);
            db[0][u] = *(const float2*)(dp + (size_t)u * OUT_F);
        }

#pragma unroll 2
        for (int st = 0; st < NST; ++st) {
            const int nx = (st + 1 < NST) ? st + 1 : NST - 1;
            const int nb = (st + 1) & 1, cb = st & 1;
            const float* wn = wp + (size_t)(nx * 4) * OUT_F;
            const float* dn = dp + (size_t)(nx * 4) * OUT_F;
#pragma unroll
            for (int u = 0; u < 4; ++u) {
                wb[nb][u] = *(const float2*)(wn + (size_t)u * OUT_F);
                db[nb][u] = *(const float2*)(dn + (size_t)u * OUT_F);
            }
            float2 rc[4];
#pragma unroll
            for (int u = 0; u < 4; ++u) {
                rc[u].x = wb[cb][u].x + DELTA_SCALE * db[cb][u].x;
                rc[u].y = wb[cb][u].y + DELTA_SCALE * db[cb][u].y;
            }
            const float* xb = &buf[kq * KT + st * 4];
#pragma unroll
            for (int j = 0; j < J; ++j) {
                const float4 xv = *(const float4*)(xb + j * IN_F);
                acc[j].x += xv.x * rc[0].x; acc[j].y += xv.x * rc[0].y;
                acc[j].x += xv.y * rc[1].x; acc[j].y += xv.y * rc[1].y;
                acc[j].x += xv.z * rc[2].x; acc[j].y += xv.z * rc[2].y;
                acc[j].x += xv.w * rc[3].x; acc[j].y += xv.w * rc[3].y;
            }
        }

        __syncthreads();
        float2* Red = (float2*)buf;
#pragma unroll
        for (int j = 0; j < J; ++j)
            Red[(kq * J + j) * 32 + c2] = acc[j];
        __syncthreads();

#pragma unroll
        for (int t = 0; t < NOUT; ++t) {
            const int oi = t * 256 + tid;
            const int j = oi >> 5, cc = oi & 31;
            if (j < nc) {
                float2 s = make_float2(0.f, 0.f);
#pragma unroll
                for (int q = 0; q < KQ; ++q) {
                    const float2 r = Red[(q * J + j) * 32 + cc];
                    s.x += r.x; s.y += r.y;
                }
                const float2 bv =
                    *(const float2*)(bias + (size_t)h * OUT_F + c0 + cc * 2);
                float* op = out + (size_t)list[s0 + j] * OUT_F + c0 + cc * 2;
                float2 res;
                res.x = s.x + bv.x;
                res.y = s.y + bv.y;
                *(float2*)op = res;
            }
        }
    }
}

extern "C" void kernel_launch(void* const* d_in, const int* in_sizes, int n_in,
                              void* d_out, int out_size, void* d_ws, size_t ws_size,
                              hipStream_t stream) {
    const float* X        = (const float*)d_in[0];
    const int*   head_ix  = (const int*)d_in[1];
    const int*   split_ix = (const int*)d_in[2];
    const float* W        = (const float*)d_in[3];
    const float* D        = (const float*)d_in[4];
    const float* bias     = (const float*)d_in[5];
    float*       out      = (float*)d_out;

    const size_t ws_need = (size_t)NPLANES * N_SAMP * OUT_F * sizeof(float); // 16MB
    if (ws_size >= ws_need) {
        float* ws = (float*)d_ws;
        // 512 blocks (128 combos x 4 k-quarters), barrier-free k-loop,
        // every W/D request dwordx4 with 1KB/wave coverage.
        lms_partial4<<<dim3(N_GROUPS * NKB), 256, 0, stream>>>(
            X, head_ix, split_ix, W, D, ws);
        // 512 blocks: 16 MB read + 2 MB write, bias folded.
        lms_reduce<<<dim3((N_SAMP * OUT_F / 4) / 256), 256, 0, stream>>>(
            ws, head_ix, bias, out);
    } else {
        // verified R7 fused fallback
        dim3 gf(OUT_F / 64, N_GROUPS);
        lms_fused<<<gf, 256, 0, stream>>>(X, head_ix, split_ix, W, D, bias, out);
    }
}

// Round 7
// 237.746 us; speedup vs baseline: 1.1323x; 1.0684x over previous
//
#include <hip/hip_runtime.h>

#define N_SAMP   1024
#define IN_F     512
#define OUT_F    512
#define N_HEADS  32
#define N_SPLITS 4
#define N_GROUPS (N_HEADS * N_SPLITS)
#define DELTA_SCALE 0.1f

// R12: R11 retry -- __builtin_nontemporal_* requires a NATIVE clang vector
// type (ext_vector_type), not HIP's float2 class. Same experiment:
// R7 fused kernel (86 us verified) + nontemporal loads on the D stream +
// nontemporal out stores. Single-variable cache-path test.
//
// Evidence: unique-byte supply is flat at ~2.4-3.0 TB/s across R7-R10
// despite 2x wave-count, 2x request-width, stripe-vs-row geometry, and
// XCD pinning -- demand-side levers are exhausted. The shared mechanism
// is plain cached loads streaming ~160 MB of single-use data through the
// L1/L2 allocate path at 100% miss rate. D (128 MB, read by exactly ONE
// block per panel -- zero reuse anywhere) bypasses via nt; W stays cached
// (4 split-blocks share each panel in L2), X cached (8 col-tile blocks
// share each row), bias cached.

typedef float f32x2 __attribute__((ext_vector_type(2)));

__device__ __forceinline__ f32x2 nt_load2(const float* p) {
    return __builtin_nontemporal_load((const f32x2*)p);
}
__device__ __forceinline__ void nt_store2(float* p, f32x2 v) {
    __builtin_nontemporal_store(v, (f32x2*)p);
}

__global__ __launch_bounds__(256, 4) void lms_fused_nt(
    const float* __restrict__ X, const int* __restrict__ head_ix,
    const int* __restrict__ split_ix, const float* __restrict__ W,
    const float* __restrict__ D, const float* __restrict__ bias,
    float* __restrict__ out)
{
    constexpr int J    = 16;           // samples per chunk
    constexpr int KQ   = 8;            // k-split ways
    constexpr int KT   = IN_F / KQ;    // 64 k rows per thread
    constexpr int NST  = KT / 4;       // 16 steps of 4 rows
    constexpr int NOUT = (J * 32) / 256;  // 2

    __shared__ float buf[J * IN_F];    // Xs[J][512] <-> Red[KQ][J][32] float2
    __shared__ int   list[N_SAMP];
    __shared__ int   wsum[4];

    const int g    = blockIdx.y;           // combo = h*N_SPLITS + s
    const int h    = g >> 2;               // N_SPLITS == 4
    const int c0   = blockIdx.x * 64;
    const int tid  = threadIdx.x;
    const int c2   = tid & 31;             // col pair
    const int kq   = tid >> 5;             // k-eighth
    const int lane = tid & 63;
    const int wave = tid >> 6;

    // deterministic order-preserving compaction of samples matching combo g
    int run = 0;
    for (int r = 0; r < N_SAMP / 256; ++r) {
        const int i   = r * 256 + tid;
        const int key = head_ix[i] * N_SPLITS + split_ix[i];
        const bool hit = (key == g);
        const unsigned long long m = __ballot(hit);
        if (lane == 0) wsum[wave] = __popcll(m);
        __syncthreads();
        int base = run;
        for (int w = 0; w < 4; ++w)
            if (w < wave) base += wsum[w];
        if (hit)
            list[base + __popcll(m & ((1ULL << lane) - 1ULL))] = i;
        run += wsum[0] + wsum[1] + wsum[2] + wsum[3];
        __syncthreads();               // wsum consumed before next round
    }
    const int total = run;
    if (total == 0) return;            // block-uniform

    // thread's stripes: rows kq*KT .. kq*KT+63, cols c0+2*c2 (+1)
    const size_t roff = (size_t)(kq * KT) * OUT_F + c0 + c2 * 2;
    const float* wp = W + (size_t)h * (IN_F * OUT_F) + roff;
    const float* dp = D + (size_t)g * (IN_F * OUT_F) + roff;

    for (int s0 = 0; s0 < total; s0 += J) {
        const int nc = min(total - s0, J);

        __syncthreads();               // buf may still hold previous Red
        for (int i = tid; i < J * (IN_F / 4); i += 256) {
            const int s = i >> 7, q = i & 127;
            float4 v = make_float4(0.f, 0.f, 0.f, 0.f);
            if (s < nc)
                v = *(const float4*)(X + (size_t)list[s0 + s] * IN_F + q * 4);
            *(float4*)(&buf[s * IN_F + q * 4]) = v;
        }
        __syncthreads();

        float2 acc[J];
#pragma unroll
        for (int j = 0; j < J; ++j) { acc[j].x = 0.f; acc[j].y = 0.f; }

        // distance-1 double-buffered 4-row batches of BOTH W (cached) and
        // D (nontemporal: single-use stream, bypass cache allocate)
        float2 wb[2][4];
        f32x2  db[2][4];
#pragma unroll
        for (int u = 0; u < 4; ++u) {
            wb[0][u] = *(const float2*)(wp + (size_t)u * OUT_F);
            db[0][u] = nt_load2(dp + (size_t)u * OUT_F);
        }

#pragma unroll 2
        for (int st = 0; st < NST; ++st) {
            // prefetch next 4-row batch (clamped tail keeps body branch-free)
            const int nx = (st + 1 < NST) ? st + 1 : NST - 1;
            const int nb = (st + 1) & 1, cb = st & 1;
            const float* wn = wp + (size_t)(nx * 4) * OUT_F;
            const float* dn = dp + (size_t)(nx * 4) * OUT_F;
#pragma unroll
            for (int u = 0; u < 4; ++u) {
                wb[nb][u] = *(const float2*)(wn + (size_t)u * OUT_F);
                db[nb][u] = nt_load2(dn + (size_t)u * OUT_F);
            }

            // combined weight for this 4-row batch
            float2 rc[4];
#pragma unroll
            for (int u = 0; u < 4; ++u) {
                rc[u].x = wb[cb][u].x + DELTA_SCALE * db[cb][u].x;
                rc[u].y = wb[cb][u].y + DELTA_SCALE * db[cb][u].y;
            }

            const float* xb = &buf[kq * KT + st * 4];
#pragma unroll
            for (int j = 0; j < J; ++j) {
                const float4 xv = *(const float4*)(xb + j * IN_F); // broadcast
                acc[j].x += xv.x * rc[0].x; acc[j].y += xv.x * rc[0].y;
                acc[j].x += xv.y * rc[1].x; acc[j].y += xv.y * rc[1].y;
                acc[j].x += xv.z * rc[2].x; acc[j].y += xv.z * rc[2].y;
                acc[j].x += xv.w * rc[3].x; acc[j].y += xv.w * rc[3].y;
            }
        }

        __syncthreads();               // Xs fully consumed; reuse buf as Red
        float2* Red = (float2*)buf;    // [KQ][J][32]
#pragma unroll
        for (int j = 0; j < J; ++j)
            Red[(kq * J + j) * 32 + c2] = acc[j];
        __syncthreads();

        // sole-owner epilogue: sum the 8 k-partials, add bias, nt store
#pragma unroll
        for (int t = 0; t < NOUT; ++t) {
            const int oi = t * 256 + tid;
            const int j = oi >> 5, cc = oi & 31;
            if (j < nc) {
                float2 s = make_float2(0.f, 0.f);
#pragma unroll
                for (int q = 0; q < KQ; ++q) {
                    const float2 r = Red[(q * J + j) * 32 + cc];
                    s.x += r.x; s.y += r.y;
                }
                const float2 bv =
                    *(const float2*)(bias + (size_t)h * OUT_F + c0 + cc * 2);
                float* op = out + (size_t)list[s0 + j] * OUT_F + c0 + cc * 2;
                f32x2 res;
                res.x = s.x + bv.x;
                res.y = s.y + bv.y;
                nt_store2(op, res);
            }
        }
    }
}

extern "C" void kernel_launch(void* const* d_in, const int* in_sizes, int n_in,
                              void* d_out, int out_size, void* d_ws, size_t ws_size,
                              hipStream_t stream) {
    const float* X        = (const float*)d_in[0];
    const int*   head_ix  = (const int*)d_in[1];
    const int*   split_ix = (const int*)d_in[2];
    const float* W        = (const float*)d_in[3];
    const float* D        = (const float*)d_in[4];
    const float* bias     = (const float*)d_in[5];
    float*       out      = (float*)d_out;

    // 128 combos x 8 col-tiles = 1024 blocks = 4/CU (36.9 KB LDS),
    // 16 waves/CU. Single dispatch; out written exactly once, bias folded.
    dim3 gf(OUT_F / 64, N_GROUPS);
    lms_fused_nt<<<gf, 256, 0, stream>>>(X, head_ix, split_ix, W, D, bias, out);
}